// Round 22
// baseline (146.318 us; speedup 1.0000x reference)
//
#include <hip/hip_runtime.h>
#include <hip/hip_bf16.h>

typedef unsigned short u16;
typedef unsigned int u32;
typedef __attribute__((ext_vector_type(8))) short bf16x8;
typedef __attribute__((ext_vector_type(4))) float f32x4;
typedef __attribute__((ext_vector_type(16))) float f32x16;
typedef __attribute__((ext_vector_type(2))) unsigned int u32x2;
typedef __attribute__((ext_vector_type(4))) unsigned int u32x4;

#define S_LEN 4096
#define DHEAD 128
#define NHEAD 8
#define NBATCH 2

__device__ __forceinline__ u16 f2b(float f) {
  __hip_bfloat16 h = __float2bfloat16(f);
  return *(u16*)&h;
}

__device__ __forceinline__ f32x4 mfma16(bf16x8 a, bf16x8 b, f32x4 c) {
  return __builtin_amdgcn_mfma_f32_16x16x32_bf16(a, b, c, 0, 0, 0);
}
__device__ __forceinline__ f32x16 mfma32(bf16x8 a, bf16x8 b, f32x16 c) {
  return __builtin_amdgcn_mfma_f32_32x32x16_bf16(a, b, c, 0, 0, 0);
}

__device__ __forceinline__ f32x4 zero4() { f32x4 z = {0.f, 0.f, 0.f, 0.f}; return z; }

__device__ __forceinline__ u32 cvtpk(float lo, float hi) {
  u32 r;
  asm("v_cvt_pk_bf16_f32 %0, %1, %2" : "=v"(r) : "v"(lo), "v"(hi));
  return r;
}
__device__ __forceinline__ u32x2 pswap(u32 a, u32 b) {
  return __builtin_amdgcn_permlane32_swap(a, b, false, false);
}

// pack C-layout regs (row offset (r&3)+8*(r>>2)+4*h5, col=lane&31) into two
// A-operand frags. Verified by the attn P->PV path (refcheck) since r15.
__device__ __forceinline__ void packA(const float* pf, bf16x8& pa0, bf16x8& pa1) {
  u32 cv0 = cvtpk(pf[0], pf[1]), cv1 = cvtpk(pf[2], pf[3]);
  u32 cv2 = cvtpk(pf[4], pf[5]), cv3 = cvtpk(pf[6], pf[7]);
  u32 cv4 = cvtpk(pf[8], pf[9]), cv5 = cvtpk(pf[10], pf[11]);
  u32 cv6 = cvtpk(pf[12], pf[13]), cv7 = cvtpk(pf[14], pf[15]);
  u32x2 s0 = pswap(cv0, cv2), s1 = pswap(cv1, cv3);
  u32x2 s2 = pswap(cv4, cv6), s3 = pswap(cv5, cv7);
  u32x4 a0 = {s0.x, s1.x, s0.y, s1.y};
  u32x4 a1 = {s2.x, s3.x, s2.y, s3.y};
  pa0 = __builtin_bit_cast(bf16x8, a0);
  pa1 = __builtin_bit_cast(bf16x8, a1);
}

// async global->LDS, 16B/lane; LDS dest = wave-uniform base + lane*16
__device__ __forceinline__ void gll16(const u16* g, u16* l) {
  __builtin_amdgcn_global_load_lds(
      (const __attribute__((address_space(1))) u32*)g,
      (__attribute__((address_space(3))) u32*)l, 16, 0, 0);
}

// ---------------- V convert: coalesced frag-centric fill ----------------
__global__ void k_conv_x(const float* __restrict__ x, u16* __restrict__ VbF) {
  int idx = blockIdx.x * blockDim.x + threadIdx.x;  // 0..131071
  int b = idx >> 16;
  int t64 = (idx >> 10) & 63;
  int g = (idx >> 6) & 15;
  int l = idx & 63;
  int kh = g >> 3, m2 = (g >> 2) & 1, db = g & 3;
  int keyb = t64 * 64 + kh * 32 + m2 * 16 + (l >> 5) * 8;
  int d = db * 32 + (l & 31);
  const float* xp = x + ((size_t)b * S_LEN + keyb) * DHEAD + d;
  u16 o[8];
#pragma unroll
  for (int j = 0; j < 8; ++j) o[j] = f2b(xp[(size_t)j * DHEAD]);
  *(bf16x8*)(VbF + (size_t)idx * 8) = *(const bf16x8*)o;
}

__global__ void k_conv_w(const float* __restrict__ Wq, const float* __restrict__ Wk,
                         const float* __restrict__ Wo, u16* __restrict__ Wqt,
                         u16* __restrict__ Wkt, u16* __restrict__ WoB) {
  int idx = blockIdx.x * blockDim.x + threadIdx.x;
  int h = idx >> 14;
  int d = (idx >> 7) & 127;
  int e = idx & 127;
  int t = (h << 14) + (e << 7) + d;
  Wqt[t] = f2b(Wq[idx]);
  Wkt[t] = f2b(Wk[idx]);
  WoB[idx] = f2b(Wo[idx]);
}

// ---------------- Q/K projection: fragment-native outputs ----------------
__global__ __launch_bounds__(256) void k_proj(const float* __restrict__ x,
                                              const u16* __restrict__ Wqt,
                                              const u16* __restrict__ Wkt,
                                              u16* __restrict__ QbF, u16* __restrict__ KbF) {
  int wid = threadIdx.x >> 6;
  int lane = threadIdx.x & 63;
  int qt = blockIdx.x * 4 + wid;     // 0..127 (32-row tile)
  int h = blockIdx.y, z = blockIdx.z;
  int b = z >> 1, w = z & 1;
  int bh = b * NHEAD + h;
  int l31 = lane & 31, h5 = lane >> 5;
  int sb = qt * 32;

  const float* xp = x + ((size_t)b * S_LEN + sb + l31) * DHEAD;
  bf16x8 bx[8];
#pragma unroll
  for (int dk = 0; dk < 8; ++dk) {
    f32x4 lo = *(const f32x4*)(xp + dk * 16 + h5 * 8);
    f32x4 hi = *(const f32x4*)(xp + dk * 16 + h5 * 8 + 4);
    u32x4 pk = {cvtpk(lo[0], lo[1]), cvtpk(lo[2], lo[3]),
                cvtpk(hi[0], hi[1]), cvtpk(hi[2], hi[3])};
    bx[dk] = __builtin_bit_cast(bf16x8, pk);
  }

  const u16* Wt = (w == 0 ? Wqt : Wkt) + (size_t)h * DHEAD * DHEAD;
  u16* Out = (w == 0 ? QbF : KbF);
  size_t obase = (w == 0)
                     ? ((size_t)(bh * 128 + qt) * 8) * 512
                     : (((size_t)bh * 64 + (qt >> 1)) * 16 + (qt & 1) * 8) * 512;

#pragma unroll
  for (int eb = 0; eb < 4; ++eb) {
    f32x16 sc;
#pragma unroll
    for (int i = 0; i < 16; ++i) sc[i] = 0.f;
#pragma unroll
    for (int dk = 0; dk < 8; ++dk) {
      bf16x8 aw = *(const bf16x8*)(Wt + (size_t)(eb * 32 + l31) * DHEAD + dk * 16 + h5 * 8);
      sc = mfma32(aw, bx[dk], sc);
    }
    float pf[16];
#pragma unroll
    for (int i = 0; i < 16; ++i) pf[i] = sc[i];
    bf16x8 pa0, pa1;
    packA(pf, pa0, pa1);
    *(bf16x8*)(Out + obase + (size_t)(eb * 2 + 0) * 512 + lane * 8) = pa0;
    *(bf16x8*)(Out + obase + (size_t)(eb * 2 + 1) * 512 + lane * 8) = pa1;
  }
}

// ---------------- causal flash attention: order-robust ledger, fewer pins ----
// r19 frame. glls issued FIRST each iteration (one sched_barrier pins them as
// the oldest vmem group); vmcnt retires in order, so any wait covering vB also
// guarantees the glls' LDS writes are visible. The pins around the tilecomps
// are removed -> compiler may software-pipeline PV(t) with QK(t+1)/vA issue.
__global__ __launch_bounds__(512) void k_attn(const u16* __restrict__ QbF,
                                              const u16* __restrict__ KbF,
                                              const u16* __restrict__ VbF,
                                              u16* __restrict__ Yb) {
  int p = blockIdx.x;                      // 0..255
  int xcd = p & 7;
  int j2 = p >> 3;                         // 0..31
  int bh = xcd + (j2 >= 16 ? 8 : 0);       // 0..15 (same (b,h) per XCD)
  int qpj = j2 & 15;
  int b = bh >> 3, h = bh & 7;

  int tid = threadIdx.x;
  int wid = tid >> 6;                      // 0..7
  int lane = tid & 63;
  int qr = wid >> 1;                       // 0..3 (32 q-rows each)
  int kh = wid & 1;                        // key half of 64-key tile
  int l31 = lane & 31, h5 = lane >> 5;

  __shared__ __align__(16) u16 SMEM[4][8192];   // 64 KB: K 4-deep / combine scr
  __shared__ float rsbuf[2][4][32];             // 1 KB

  const u16* Kbase = KbF + (size_t)bh * 64 * 16 * 512;
  const u16* Vbase = VbF + (size_t)b * 64 * 16 * 512;

  auto issue = [&](int k0, int buf) {
    const u16* Ks = Kbase + (size_t)(k0 >> 6) * 16 * 512;
#pragma unroll
    for (int fi = 0; fi < 2; ++fi) {
      int f = wid * 2 + fi;
      gll16(Ks + f * 512 + lane * 8, &SMEM[buf][f * 512]);
    }
  };
  auto vload = [&](bf16x8 (&dst)[8], int k0) {
    const u16* Vs = Vbase + ((size_t)(k0 >> 6) * 16 + kh * 8) * 512 + lane * 8;
#pragma unroll
    for (int g = 0; g < 8; ++g) dst[g] = *(const bf16x8*)(Vs + g * 512);
  };

  const float c2 = 0.12754274816295166f;    // (1/sqrt(128)) * log2(e)
  const float clip2 = 14.426950408889634f;  // 10 * log2(e)

  auto runSeg = [&](int qblk) {
    int qb0 = qblk * 128;
    int qw = qb0 + qr * 32;
    int qrow = qw + l31;                   // this lane's q-row
    const u16* Qp = QbF + ((size_t)(bh * 128 + (qw >> 5)) * 8) * 512;

    bf16x8 bq[8];
#pragma unroll
    for (int m = 0; m < 8; ++m)
      bq[m] = *(const bf16x8*)(Qp + (size_t)m * 512 + lane * 8);

    f32x16 y0, y1, y2, y3;
#pragma unroll
    for (int i = 0; i < 16; ++i) { y0[i] = 0.f; y1[i] = 0.f; y2[i] = 0.f; y3[i] = 0.f; }
    float rs = 0.f;

    bf16x8 vA[8], vB[8];

    auto tilecomp = [&](int buf, int k0, bf16x8 (&vc)[8]) {
      f32x16 sc;
#pragma unroll
      for (int i = 0; i < 16; ++i) sc[i] = 0.f;
      __builtin_amdgcn_s_setprio(1);
#pragma unroll
      for (int m = 0; m < 8; ++m) {
        bf16x8 kf = *(const bf16x8*)&SMEM[buf][((kh * 8 + m) * 512) + lane * 8];
        sc = mfma32(kf, bq[m], sc);
      }
      __builtin_amdgcn_s_setprio(0);

      float pf[16];
      int kb = k0 + kh * 32 + h5 * 4;
      bool nomask = (k0 + kh * 32 + 31) <= qw;   // wave-uniform
      if (nomask) {
#pragma unroll
        for (int reg = 0; reg < 16; ++reg) {
          float v = __builtin_amdgcn_fmed3f(sc[reg] * c2, -clip2, clip2);
          float pc = __builtin_amdgcn_exp2f(v);
          rs += pc;
          pf[reg] = pc;
        }
      } else {
#pragma unroll
        for (int reg = 0; reg < 16; ++reg) {
          int key = kb + (reg & 3) + 8 * (reg >> 2);
          float v = __builtin_amdgcn_fmed3f(sc[reg] * c2, -clip2, clip2);
          float pc = __builtin_amdgcn_exp2f(v);
          pc = (key > qrow) ? 0.0f : pc;
          rs += pc;
          pf[reg] = pc;
        }
      }
      bf16x8 pa0, pa1;
      packA(pf, pa0, pa1);
      __builtin_amdgcn_s_setprio(1);
      y0 = mfma32(pa0, vc[0], y0);
      y0 = mfma32(pa1, vc[4], y0);
      y1 = mfma32(pa0, vc[1], y1);
      y1 = mfma32(pa1, vc[5], y1);
      y2 = mfma32(pa0, vc[2], y2);
      y2 = mfma32(pa1, vc[6], y2);
      y3 = mfma32(pa0, vc[3], y3);
      y3 = mfma32(pa1, vc[7], y3);
      __builtin_amdgcn_s_setprio(0);
    };

    int NT = 2 * qblk + 2;   // even
    issue(0, 0);
    issue(64, 1);
    vload(vA, 0);
    __syncthreads();  // prologue: full drain once per segment
    for (int t = 0; t < NT; t += 2) {
      int k0 = t * 64;
      // K-glls FIRST: pinned as the oldest vmem group of this iteration.
      if (t + 2 < NT) issue(k0 + 128, (t + 2) & 3);
      if (t + 3 < NT) issue(k0 + 192, (t + 3) & 3);
      __builtin_amdgcn_sched_barrier(0);        // only pin: glls precede all
      vload(vB, k0 + 64);                       // V(t+1)
      tilecomp(t & 3, k0, vA);                  // consumes vA (prev iter)
      if (t + 2 < NT) vload(vA, k0 + 128);      // V(t+2)
      tilecomp((t + 1) & 3, k0 + 64, vB);       // wait(vB) => glls retired too
      // vmcnt(8): direct guarantee glls+vB done; vA (newest 8) stays in flight
      asm volatile("s_waitcnt vmcnt(8)" ::: "memory");
      __builtin_amdgcn_s_barrier();
      __builtin_amdgcn_sched_barrier(0);        // no hoisting above barrier
    }

    rs += __shfl_xor(rs, 32, 64);

    float* scr = (float*)&SMEM[0][0] + qr * 4096;
    if (kh == 1) {
#pragma unroll
      for (int db = 0; db < 4; ++db) {
        const f32x16& yv = (db == 0) ? y0 : (db == 1) ? y1 : (db == 2) ? y2 : y3;
#pragma unroll
        for (int r4 = 0; r4 < 4; ++r4) {
          f32x4 ch = {yv[r4 * 4 + 0], yv[r4 * 4 + 1], yv[r4 * 4 + 2], yv[r4 * 4 + 3]};
          *(f32x4*)&scr[((db * 4 + r4) * 64 + lane) * 4] = ch;
        }
      }
      if (lane < 32) rsbuf[1][qr][lane] = rs;
    }
    __syncthreads();
    if (kh == 0) {
      float rs2 = rs + rsbuf[1][qr][l31];
      float inv = 1.0f / rs2;
      if (lane < 32) rsbuf[0][qr][lane] = inv;
#pragma unroll
      for (int db = 0; db < 4; ++db) {
        f32x16& yv = (db == 0) ? y0 : (db == 1) ? y1 : (db == 2) ? y2 : y3;
#pragma unroll
        for (int r4 = 0; r4 < 4; ++r4) {
          f32x4 ch = *(const f32x4*)&scr[((db * 4 + r4) * 64 + lane) * 4];
#pragma unroll
          for (int k = 0; k < 4; ++k) yv[r4 * 4 + k] += ch[k];
        }
      }
      u16* Yp = Yb + ((size_t)b * S_LEN + qw) * (NHEAD * DHEAD) + h * DHEAD;
#pragma unroll
      for (int db = 0; db < 4; ++db) {
        const f32x16& yv = (db == 0) ? y0 : (db == 1) ? y1 : (db == 2) ? y2 : y3;
#pragma unroll
        for (int reg = 0; reg < 16; ++reg) {
          int qp2 = (reg & 3) + 8 * (reg >> 2) + 4 * h5;
          float rv = rsbuf[0][qr][qp2];
          Yp[(size_t)qp2 * (NHEAD * DHEAD) + db * 32 + l31] = f2b(yv[reg] * rv);
        }
      }
    }
    __syncthreads();
  };

  runSeg(31 - qpj);
  runSeg(qpj);
}

// ---------------- output projection: 4 waves/block (r19 shape) ----------------
__global__ __launch_bounds__(256) void k_oproj(const u16* __restrict__ Yb,
                                               const u16* __restrict__ WoB,
                                               float* __restrict__ out) {
  int wid = threadIdx.x >> 6;
  int lane = threadIdx.x & 63;
  int mb = (blockIdx.x * 4 + wid) * 32 + blockIdx.y * 16;
  int nb = blockIdx.z * 64;
  int row16 = lane & 15, kgrp = lane >> 4;
  f32x4 acc[4];
#pragma unroll
  for (int nc = 0; nc < 4; ++nc) acc[nc] = zero4();
#pragma unroll 4
  for (int kc = 0; kc < 32; ++kc) {
    bf16x8 a0 = *(const bf16x8*)(Yb + (size_t)(mb + row16) * 1024 + kc * 32 + kgrp * 8);
#pragma unroll
    for (int nc = 0; nc < 4; ++nc) {
      bf16x8 bw =
          *(const bf16x8*)(WoB + (size_t)(nb + nc * 16 + row16) * 1024 + kc * 32 + kgrp * 8);
      acc[nc] = mfma16(a0, bw, acc[nc]);
    }
  }
#pragma unroll
  for (int nc = 0; nc < 4; ++nc)
#pragma unroll
    for (int i = 0; i < 4; ++i)
      out[(size_t)(mb + kgrp * 4 + i) * DHEAD + nb + nc * 16 + row16] = acc[nc][i];
}

extern "C" void kernel_launch(void* const* d_in, const int* in_sizes, int n_in,
                              void* d_out, int out_size, void* d_ws, size_t ws_size,
                              hipStream_t stream) {
  const float* x = (const float*)d_in[0];
  const float* Wq = (const float*)d_in[1];
  const float* Wk = (const float*)d_in[2];
  const float* Wo = (const float*)d_in[3];
  float* out = (float*)d_out;

  char* ws = (char*)d_ws;
  size_t off = 0;
  auto alloc = [&](size_t bytes) -> void* {
    void* p = ws + off;
    off += (bytes + 255) & ~(size_t)255;
    return p;
  };
  const size_t nx = (size_t)NBATCH * S_LEN * DHEAD;
  const size_t nqk = (size_t)NBATCH * NHEAD * S_LEN * DHEAD;
  u16* VbF = (u16*)alloc(nx * 2);
  u16* Wqt = (u16*)alloc((size_t)NHEAD * DHEAD * DHEAD * 2);
  u16* Wkt = (u16*)alloc((size_t)NHEAD * DHEAD * DHEAD * 2);
  u16* WoB = (u16*)alloc((size_t)DHEAD * NHEAD * DHEAD * 2);
  u16* QbF = (u16*)alloc(nqk * 2);
  u16* KbF = (u16*)alloc(nqk * 2);
  u16* Yb = (u16*)alloc(nqk * 2);
  (void)ws_size;

  k_conv_x<<<dim3(512), dim3(256), 0, stream>>>(x, VbF);
  k_conv_w<<<dim3(131072 / 256), dim3(256), 0, stream>>>(Wq, Wk, Wo, Wqt, Wkt, WoB);
  k_proj<<<dim3(S_LEN / 32 / 4, NHEAD, 2 * NBATCH), dim3(256), 0, stream>>>(x, Wqt, Wkt, QbF, KbF);
  k_attn<<<dim3(256), dim3(512), 0, stream>>>(QbF, KbF, VbF, Yb);
  k_oproj<<<dim3((NBATCH * S_LEN) / 32 / 4, 2, 2), dim3(256), 0, stream>>>(Yb, WoB, out);
}

// Round 23
// 138.918 us; speedup vs baseline: 1.0533x; 1.0533x over previous
//
#include <hip/hip_runtime.h>
#include <hip/hip_bf16.h>

typedef unsigned short u16;
typedef unsigned int u32;
typedef __attribute__((ext_vector_type(8))) short bf16x8;
typedef __attribute__((ext_vector_type(4))) float f32x4;
typedef __attribute__((ext_vector_type(16))) float f32x16;
typedef __attribute__((ext_vector_type(2))) unsigned int u32x2;
typedef __attribute__((ext_vector_type(4))) unsigned int u32x4;

#define S_LEN 4096
#define DHEAD 128
#define NHEAD 8
#define NBATCH 2

__device__ __forceinline__ u16 f2b(float f) {
  __hip_bfloat16 h = __float2bfloat16(f);
  return *(u16*)&h;
}

__device__ __forceinline__ f32x4 mfma16(bf16x8 a, bf16x8 b, f32x4 c) {
  return __builtin_amdgcn_mfma_f32_16x16x32_bf16(a, b, c, 0, 0, 0);
}
__device__ __forceinline__ f32x16 mfma32(bf16x8 a, bf16x8 b, f32x16 c) {
  return __builtin_amdgcn_mfma_f32_32x32x16_bf16(a, b, c, 0, 0, 0);
}

__device__ __forceinline__ f32x4 zero4() { f32x4 z = {0.f, 0.f, 0.f, 0.f}; return z; }

__device__ __forceinline__ u32 cvtpk(float lo, float hi) {
  u32 r;
  asm("v_cvt_pk_bf16_f32 %0, %1, %2" : "=v"(r) : "v"(lo), "v"(hi));
  return r;
}
__device__ __forceinline__ u32x2 pswap(u32 a, u32 b) {
  return __builtin_amdgcn_permlane32_swap(a, b, false, false);
}

// pack C-layout regs (row offset (r&3)+8*(r>>2)+4*h5, col=lane&31) into two
// A-operand frags. Verified by the attn P->PV path (refcheck) since r15.
__device__ __forceinline__ void packA(const float* pf, bf16x8& pa0, bf16x8& pa1) {
  u32 cv0 = cvtpk(pf[0], pf[1]), cv1 = cvtpk(pf[2], pf[3]);
  u32 cv2 = cvtpk(pf[4], pf[5]), cv3 = cvtpk(pf[6], pf[7]);
  u32 cv4 = cvtpk(pf[8], pf[9]), cv5 = cvtpk(pf[10], pf[11]);
  u32 cv6 = cvtpk(pf[12], pf[13]), cv7 = cvtpk(pf[14], pf[15]);
  u32x2 s0 = pswap(cv0, cv2), s1 = pswap(cv1, cv3);
  u32x2 s2 = pswap(cv4, cv6), s3 = pswap(cv5, cv7);
  u32x4 a0 = {s0.x, s1.x, s0.y, s1.y};
  u32x4 a1 = {s2.x, s3.x, s2.y, s3.y};
  pa0 = __builtin_bit_cast(bf16x8, a0);
  pa1 = __builtin_bit_cast(bf16x8, a1);
}

// async global->LDS, 16B/lane; LDS dest = wave-uniform base + lane*16
__device__ __forceinline__ void gll16(const u16* g, u16* l) {
  __builtin_amdgcn_global_load_lds(
      (const __attribute__((address_space(1))) u32*)g,
      (__attribute__((address_space(3))) u32*)l, 16, 0, 0);
}

// ---------------- fused converts: V frag-fill + weight casts ----------------
// blocks 0..511: VbF fill (frag-centric, coalesced). blocks 512..1023: W casts.
__global__ void k_conv(const float* __restrict__ x, u16* __restrict__ VbF,
                       const float* __restrict__ Wq, const float* __restrict__ Wk,
                       const float* __restrict__ Wo, u16* __restrict__ Wqt,
                       u16* __restrict__ Wkt, u16* __restrict__ WoB) {
  int bid = blockIdx.x;
  if (bid < 512) {
    int idx = bid * blockDim.x + threadIdx.x;  // 0..131071
    int b = idx >> 16;
    int t64 = (idx >> 10) & 63;
    int g = (idx >> 6) & 15;
    int l = idx & 63;
    int kh = g >> 3, m2 = (g >> 2) & 1, db = g & 3;
    int keyb = t64 * 64 + kh * 32 + m2 * 16 + (l >> 5) * 8;
    int d = db * 32 + (l & 31);
    const float* xp = x + ((size_t)b * S_LEN + keyb) * DHEAD + d;
    u16 o[8];
#pragma unroll
    for (int j = 0; j < 8; ++j) o[j] = f2b(xp[(size_t)j * DHEAD]);
    *(bf16x8*)(VbF + (size_t)idx * 8) = *(const bf16x8*)o;
  } else {
    int idx = (bid - 512) * blockDim.x + threadIdx.x;  // 0..131071
    int h = idx >> 14;
    int d = (idx >> 7) & 127;
    int e = idx & 127;
    int t = (h << 14) + (e << 7) + d;
    Wqt[t] = f2b(Wq[idx]);
    Wkt[t] = f2b(Wk[idx]);
    WoB[idx] = f2b(Wo[idx]);
  }
}

// ---------------- Q/K projection: fragment-native outputs ----------------
__global__ __launch_bounds__(256) void k_proj(const float* __restrict__ x,
                                              const u16* __restrict__ Wqt,
                                              const u16* __restrict__ Wkt,
                                              u16* __restrict__ QbF, u16* __restrict__ KbF) {
  int wid = threadIdx.x >> 6;
  int lane = threadIdx.x & 63;
  int qt = blockIdx.x * 4 + wid;     // 0..127 (32-row tile)
  int h = blockIdx.y, z = blockIdx.z;
  int b = z >> 1, w = z & 1;
  int bh = b * NHEAD + h;
  int l31 = lane & 31, h5 = lane >> 5;
  int sb = qt * 32;

  const float* xp = x + ((size_t)b * S_LEN + sb + l31) * DHEAD;
  bf16x8 bx[8];
#pragma unroll
  for (int dk = 0; dk < 8; ++dk) {
    f32x4 lo = *(const f32x4*)(xp + dk * 16 + h5 * 8);
    f32x4 hi = *(const f32x4*)(xp + dk * 16 + h5 * 8 + 4);
    u32x4 pk = {cvtpk(lo[0], lo[1]), cvtpk(lo[2], lo[3]),
                cvtpk(hi[0], hi[1]), cvtpk(hi[2], hi[3])};
    bx[dk] = __builtin_bit_cast(bf16x8, pk);
  }

  const u16* Wt = (w == 0 ? Wqt : Wkt) + (size_t)h * DHEAD * DHEAD;
  u16* Out = (w == 0 ? QbF : KbF);
  size_t obase = (w == 0)
                     ? ((size_t)(bh * 128 + qt) * 8) * 512
                     : (((size_t)bh * 64 + (qt >> 1)) * 16 + (qt & 1) * 8) * 512;

#pragma unroll
  for (int eb = 0; eb < 4; ++eb) {
    f32x16 sc;
#pragma unroll
    for (int i = 0; i < 16; ++i) sc[i] = 0.f;
#pragma unroll
    for (int dk = 0; dk < 8; ++dk) {
      bf16x8 aw = *(const bf16x8*)(Wt + (size_t)(eb * 32 + l31) * DHEAD + dk * 16 + h5 * 8);
      sc = mfma32(aw, bx[dk], sc);
    }
    float pf[16];
#pragma unroll
    for (int i = 0; i < 16; ++i) pf[i] = sc[i];
    bf16x8 pa0, pa1;
    packA(pf, pa0, pa1);
    *(bf16x8*)(Out + obase + (size_t)(eb * 2 + 0) * 512 + lane * 8) = pa0;
    *(bf16x8*)(Out + obase + (size_t)(eb * 2 + 1) * 512 + lane * 8) = pa1;
  }
}

// ---------------- causal flash attention (r19 structure, known-best) ---------
__global__ __launch_bounds__(512) void k_attn(const u16* __restrict__ QbF,
                                              const u16* __restrict__ KbF,
                                              const u16* __restrict__ VbF,
                                              u16* __restrict__ Yb) {
  int p = blockIdx.x;                      // 0..255
  int xcd = p & 7;
  int j2 = p >> 3;                         // 0..31
  int bh = xcd + (j2 >= 16 ? 8 : 0);       // 0..15 (same (b,h) per XCD)
  int qpj = j2 & 15;
  int b = bh >> 3, h = bh & 7;

  int tid = threadIdx.x;
  int wid = tid >> 6;                      // 0..7
  int lane = tid & 63;
  int qr = wid >> 1;                       // 0..3 (32 q-rows each)
  int kh = wid & 1;                        // key half of 64-key tile
  int l31 = lane & 31, h5 = lane >> 5;

  __shared__ __align__(16) u16 SMEM[4][8192];   // 64 KB: K 4-deep / combine scr
  __shared__ float rsbuf[2][4][32];             // 1 KB

  const u16* Kbase = KbF + (size_t)bh * 64 * 16 * 512;
  const u16* Vbase = VbF + (size_t)b * 64 * 16 * 512;

  auto issue = [&](int k0, int buf) {
    const u16* Ks = Kbase + (size_t)(k0 >> 6) * 16 * 512;
#pragma unroll
    for (int fi = 0; fi < 2; ++fi) {
      int f = wid * 2 + fi;
      gll16(Ks + f * 512 + lane * 8, &SMEM[buf][f * 512]);
    }
  };
  auto vload = [&](bf16x8 (&dst)[8], int k0) {
    const u16* Vs = Vbase + ((size_t)(k0 >> 6) * 16 + kh * 8) * 512 + lane * 8;
#pragma unroll
    for (int g = 0; g < 8; ++g) dst[g] = *(const bf16x8*)(Vs + g * 512);
  };

  const float c2 = 0.12754274816295166f;    // (1/sqrt(128)) * log2(e)
  const float clip2 = 14.426950408889634f;  // 10 * log2(e)

  auto runSeg = [&](int qblk) {
    int qb0 = qblk * 128;
    int qw = qb0 + qr * 32;
    int qrow = qw + l31;                   // this lane's q-row
    const u16* Qp = QbF + ((size_t)(bh * 128 + (qw >> 5)) * 8) * 512;

    bf16x8 bq[8];
#pragma unroll
    for (int m = 0; m < 8; ++m)
      bq[m] = *(const bf16x8*)(Qp + (size_t)m * 512 + lane * 8);

    f32x16 y0, y1, y2, y3;
#pragma unroll
    for (int i = 0; i < 16; ++i) { y0[i] = 0.f; y1[i] = 0.f; y2[i] = 0.f; y3[i] = 0.f; }
    float rs = 0.f;

    bf16x8 vA[8], vB[8];

    auto tilecomp = [&](int buf, int k0, bf16x8 (&vc)[8]) {
      f32x16 sc;
#pragma unroll
      for (int i = 0; i < 16; ++i) sc[i] = 0.f;
      __builtin_amdgcn_s_setprio(1);
#pragma unroll
      for (int m = 0; m < 8; ++m) {
        bf16x8 kf = *(const bf16x8*)&SMEM[buf][((kh * 8 + m) * 512) + lane * 8];
        sc = mfma32(kf, bq[m], sc);
      }
      __builtin_amdgcn_s_setprio(0);

      float pf[16];
      int kb = k0 + kh * 32 + h5 * 4;
      bool nomask = (k0 + kh * 32 + 31) <= qw;   // wave-uniform
      if (nomask) {
#pragma unroll
        for (int reg = 0; reg < 16; ++reg) {
          float v = __builtin_amdgcn_fmed3f(sc[reg] * c2, -clip2, clip2);
          float pc = __builtin_amdgcn_exp2f(v);
          rs += pc;
          pf[reg] = pc;
        }
      } else {
#pragma unroll
        for (int reg = 0; reg < 16; ++reg) {
          int key = kb + (reg & 3) + 8 * (reg >> 2);
          float v = __builtin_amdgcn_fmed3f(sc[reg] * c2, -clip2, clip2);
          float pc = __builtin_amdgcn_exp2f(v);
          pc = (key > qrow) ? 0.0f : pc;
          rs += pc;
          pf[reg] = pc;
        }
      }
      bf16x8 pa0, pa1;
      packA(pf, pa0, pa1);
      __builtin_amdgcn_s_setprio(1);
      y0 = mfma32(pa0, vc[0], y0);
      y0 = mfma32(pa1, vc[4], y0);
      y1 = mfma32(pa0, vc[1], y1);
      y1 = mfma32(pa1, vc[5], y1);
      y2 = mfma32(pa0, vc[2], y2);
      y2 = mfma32(pa1, vc[6], y2);
      y3 = mfma32(pa0, vc[3], y3);
      y3 = mfma32(pa1, vc[7], y3);
      __builtin_amdgcn_s_setprio(0);
    };

    int NT = 2 * qblk + 2;   // even
    issue(0, 0);
    issue(64, 1);
    vload(vA, 0);
    __syncthreads();  // prologue: full drain once per segment
    for (int t = 0; t < NT; t += 2) {
      int k0 = t * 64;
      vload(vB, k0 + 64);                       // V(t+1): oldest vmem group
      if (t + 2 < NT) issue(k0 + 128, (t + 2) & 3);
      if (t + 3 < NT) issue(k0 + 192, (t + 3) & 3);
      __builtin_amdgcn_sched_barrier(0);
      tilecomp(t & 3, k0, vA);
      if (t + 2 < NT) vload(vA, k0 + 128);
      __builtin_amdgcn_sched_barrier(0);
      tilecomp((t + 1) & 3, k0 + 64, vB);
      asm volatile("s_waitcnt vmcnt(8)" ::: "memory");  // keep vA in flight
      __builtin_amdgcn_s_barrier();
      __builtin_amdgcn_sched_barrier(0);
    }

    rs += __shfl_xor(rs, 32, 64);

    float* scr = (float*)&SMEM[0][0] + qr * 4096;
    if (kh == 1) {
#pragma unroll
      for (int db = 0; db < 4; ++db) {
        const f32x16& yv = (db == 0) ? y0 : (db == 1) ? y1 : (db == 2) ? y2 : y3;
#pragma unroll
        for (int r4 = 0; r4 < 4; ++r4) {
          f32x4 ch = {yv[r4 * 4 + 0], yv[r4 * 4 + 1], yv[r4 * 4 + 2], yv[r4 * 4 + 3]};
          *(f32x4*)&scr[((db * 4 + r4) * 64 + lane) * 4] = ch;
        }
      }
      if (lane < 32) rsbuf[1][qr][lane] = rs;
    }
    __syncthreads();
    if (kh == 0) {
      float rs2 = rs + rsbuf[1][qr][l31];
      float inv = 1.0f / rs2;
      if (lane < 32) rsbuf[0][qr][lane] = inv;
#pragma unroll
      for (int db = 0; db < 4; ++db) {
        f32x16& yv = (db == 0) ? y0 : (db == 1) ? y1 : (db == 2) ? y2 : y3;
#pragma unroll
        for (int r4 = 0; r4 < 4; ++r4) {
          f32x4 ch = *(const f32x4*)&scr[((db * 4 + r4) * 64 + lane) * 4];
#pragma unroll
          for (int k = 0; k < 4; ++k) yv[r4 * 4 + k] += ch[k];
        }
      }
      u16* Yp = Yb + ((size_t)b * S_LEN + qw) * (NHEAD * DHEAD) + h * DHEAD;
#pragma unroll
      for (int db = 0; db < 4; ++db) {
        const f32x16& yv = (db == 0) ? y0 : (db == 1) ? y1 : (db == 2) ? y2 : y3;
#pragma unroll
        for (int reg = 0; reg < 16; ++reg) {
          int qp2 = (reg & 3) + 8 * (reg >> 2) + 4 * h5;
          float rv = rsbuf[0][qr][qp2];
          Yp[(size_t)qp2 * (NHEAD * DHEAD) + db * 32 + l31] = f2b(yv[reg] * rv);
        }
      }
    }
    __syncthreads();
  };

  runSeg(31 - qpj);
  runSeg(qpj);
}

// ---------------- output projection: 4 waves/block (r19 shape) ----------------
__global__ __launch_bounds__(256) void k_oproj(const u16* __restrict__ Yb,
                                               const u16* __restrict__ WoB,
                                               float* __restrict__ out) {
  int wid = threadIdx.x >> 6;
  int lane = threadIdx.x & 63;
  int mb = (blockIdx.x * 4 + wid) * 32 + blockIdx.y * 16;
  int nb = blockIdx.z * 64;
  int row16 = lane & 15, kgrp = lane >> 4;
  f32x4 acc[4];
#pragma unroll
  for (int nc = 0; nc < 4; ++nc) acc[nc] = zero4();
#pragma unroll 4
  for (int kc = 0; kc < 32; ++kc) {
    bf16x8 a0 = *(const bf16x8*)(Yb + (size_t)(mb + row16) * 1024 + kc * 32 + kgrp * 8);
#pragma unroll
    for (int nc = 0; nc < 4; ++nc) {
      bf16x8 bw =
          *(const bf16x8*)(WoB + (size_t)(nb + nc * 16 + row16) * 1024 + kc * 32 + kgrp * 8);
      acc[nc] = mfma16(a0, bw, acc[nc]);
    }
  }
#pragma unroll
  for (int nc = 0; nc < 4; ++nc)
#pragma unroll
    for (int i = 0; i < 4; ++i)
      out[(size_t)(mb + kgrp * 4 + i) * DHEAD + nb + nc * 16 + row16] = acc[nc][i];
}

extern "C" void kernel_launch(void* const* d_in, const int* in_sizes, int n_in,
                              void* d_out, int out_size, void* d_ws, size_t ws_size,
                              hipStream_t stream) {
  const float* x = (const float*)d_in[0];
  const float* Wq = (const float*)d_in[1];
  const float* Wk = (const float*)d_in[2];
  const float* Wo = (const float*)d_in[3];
  float* out = (float*)d_out;

  char* ws = (char*)d_ws;
  size_t off = 0;
  auto alloc = [&](size_t bytes) -> void* {
    void* p = ws + off;
    off += (bytes + 255) & ~(size_t)255;
    return p;
  };
  const size_t nx = (size_t)NBATCH * S_LEN * DHEAD;
  const size_t nqk = (size_t)NBATCH * NHEAD * S_LEN * DHEAD;
  u16* VbF = (u16*)alloc(nx * 2);
  u16* Wqt = (u16*)alloc((size_t)NHEAD * DHEAD * DHEAD * 2);
  u16* Wkt = (u16*)alloc((size_t)NHEAD * DHEAD * DHEAD * 2);
  u16* WoB = (u16*)alloc((size_t)DHEAD * NHEAD * DHEAD * 2);
  u16* QbF = (u16*)alloc(nqk * 2);
  u16* KbF = (u16*)alloc(nqk * 2);
  u16* Yb = (u16*)alloc(nqk * 2);
  (void)ws_size;

  k_conv<<<dim3(1024), dim3(256), 0, stream>>>(x, VbF, Wq, Wk, Wo, Wqt, Wkt, WoB);
  k_proj<<<dim3(S_LEN / 32 / 4, NHEAD, 2 * NBATCH), dim3(256), 0, stream>>>(x, Wqt, Wkt, QbF, KbF);
  k_attn<<<dim3(256), dim3(512), 0, stream>>>(QbF, KbF, VbF, Yb);
  k_oproj<<<dim3((NBATCH * S_LEN) / 32 / 4, 2, 2), dim3(256), 0, stream>>>(Yb, WoB, out);
}